// Round 2
// baseline (235.742 us; speedup 1.0000x reference)
//
#include <hip/hip_runtime.h>
#include <hip/hip_bf16.h>

// nnvit_82042465288319 on MI355X (gfx950). B=262144 rows; y[5][32]; 2 layers
// (H=8, HD=4); out = y[0] after layer 1. Inputs f32 (dtype probe keeps a bf16
// path for safety).
//
// Round 5 design (pi-permuted channels; VMEM + pack/unpack diet):
//  - wave = 16 batch elements; lane (quad=lane>>4, nl=lane&15).
//  - Channel permutation pi(8q+j) = 4q+(j&3)+(j>=4?16:0); prep pi-permutes the
//    input columns of qkv_w/proj_w -> zero shuffles anywhere (round-4 win).
//  - V stays f32 (raw MFMA acc) -> no pk/unpack round-trip (-120 VALU/wave).
//  - pos_bias padded to [layer][head][n][8] f32 (32B-aligned) in prep ->
//    attention loads pb per row as dwordx4+dword (60 -> 24 VMEM/lane).
//  - o-accum via 2-wide elementwise fma (v_pk_fma_f32 eligible).
//  - Softmax: no max-shift (logits bounded, exp2-safe), log2e pre-folded.
//  - LDS = 0. VGPR target <= 48 (8 waves/SIMD).

#define NTOK 5

typedef decltype(__builtin_amdgcn_cvt_pkrtz(0.0f, 0.0f)) half2_t;
using half8_t = __attribute__((ext_vector_type(8))) _Float16;
using f32x4 = __attribute__((ext_vector_type(4))) float;
using f32x2 = __attribute__((ext_vector_type(2))) float;

union H2 { half2_t h; unsigned int u; };
union H8 { half8_t h; uint4 u4; unsigned int u[4]; };

__device__ __forceinline__ half2_t u2h(unsigned int x) { H2 c; c.u = x; return c.h; }
__device__ __forceinline__ unsigned int h2u(half2_t h) { H2 c; c.h = h; return c.u; }
__device__ __forceinline__ unsigned int pk(float a, float b) {
  return h2u(__builtin_amdgcn_cvt_pkrtz(a, b));
}
__device__ __forceinline__ float bf2f(unsigned short u) {
  union { unsigned int u; float f; } c; c.u = ((unsigned int)u) << 16; return c.f;
}
__device__ __forceinline__ half2_t bfpair2h2(unsigned int u) {
  union { unsigned int u; float f; } lo, hi;
  lo.u = u << 16;
  hi.u = u & 0xffff0000u;
  return __builtin_amdgcn_cvt_pkrtz(lo.f, hi.f);  // exact: bf16 fits fp16 range here
}
// round-to-nearest-even f32 pair -> packed bf16 pair
__device__ __forceinline__ unsigned int f2bfpair(float a, float b) {
  unsigned int ua = __float_as_uint(a), ub = __float_as_uint(b);
  ua = (ua + 0x7fffu + ((ua >> 16) & 1u)) >> 16;
  ub = (ub + 0x7fffu + ((ub >> 16) & 1u)) & 0xffff0000u;
  return ua | ub;
}

// dtype probe: low 16 bits of each word form a normal-band bf16 exponent iff bf16
__device__ __forceinline__ int detect_bf16(const unsigned int* __restrict__ p) {
  int cnt = 0;
#pragma unroll
  for (int i = 0; i < 64; ++i) {
    unsigned int e = (p[i] >> 7) & 0xffu;
    cnt += (e >= 96u && e <= 150u) ? 1 : 0;
  }
  return (cnt >= 40) ? 1 : 0;
}

// channel permutation: pi(8q+j) = 4q + (j&3) + (j>=4 ? 16 : 0)
__device__ __forceinline__ int permch(int pos) {
  return 4 * (pos >> 3) + (pos & 3) + ((pos & 4) ? 16 : 0);
}

// ---------------- prep ----------------
// ws: wqkv u32[3072]@0 | wproj u32[1024]@12288 | bqkv f32[192]@16384
//     bproj f32[64]@17152 | pb f32[640]@17408 (layout [l][h][n][8], *log2e)
//     | flag int@19968
__global__ void prep_kernel(const void* __restrict__ xraw,
                            const void* __restrict__ qkv_w, const void* __restrict__ qkv_b,
                            const void* __restrict__ proj_w, const void* __restrict__ proj_b,
                            const void* __restrict__ pos_b,
                            unsigned int* __restrict__ wqkv, unsigned int* __restrict__ wproj,
                            float* __restrict__ bqkv, float* __restrict__ bproj,
                            float* __restrict__ pb, int* __restrict__ flag) {
  const int t = threadIdx.x;  // single block of 256
  const int isbf = detect_bf16((const unsigned int*)xraw);
  if (t == 0) *flag = isbf;
  const float LOG2E = 1.44269504f;
  if (isbf) {
    const unsigned short* qw = (const unsigned short*)qkv_w;
    const unsigned short* qb = (const unsigned short*)qkv_b;
    const unsigned short* pw = (const unsigned short*)proj_w;
    const unsigned short* pbb = (const unsigned short*)proj_b;
    const unsigned short* pp = (const unsigned short*)pos_b;
    for (int i = t; i < 3072; i += 256) {
      const int row = i >> 4, cp = (i & 15) * 2;
      wqkv[i] = h2u(__builtin_amdgcn_cvt_pkrtz(bf2f(qw[row * 32 + permch(cp)]),
                                               bf2f(qw[row * 32 + permch(cp + 1)])));
    }
    for (int i = t; i < 1024; i += 256) {
      const int row = i >> 4, cp = (i & 15) * 2;
      wproj[i] = h2u(__builtin_amdgcn_cvt_pkrtz(bf2f(pw[row * 32 + permch(cp)]),
                                                bf2f(pw[row * 32 + permch(cp + 1)])));
    }
    for (int i = t; i < 192; i += 256) bqkv[i] = bf2f(qb[i]);
    for (int i = t; i < 64; i += 256) bproj[i] = bf2f(pbb[i]);
    for (int i = t; i < 640; i += 256) {
      const int m = i & 7, r = i >> 3;       // r = lh*5 + n, lh in [0,16)
      const int n = r % 5, lh = r / 5;
      pb[i] = (m < 5) ? bf2f(pp[lh * 25 + n * 5 + m]) * LOG2E : 0.0f;
    }
  } else {
    const float* qw = (const float*)qkv_w;
    const float* qb = (const float*)qkv_b;
    const float* pw = (const float*)proj_w;
    const float* pbb = (const float*)proj_b;
    const float* pp = (const float*)pos_b;
    for (int i = t; i < 3072; i += 256) {
      const int row = i >> 4, cp = (i & 15) * 2;
      wqkv[i] = h2u(__builtin_amdgcn_cvt_pkrtz(qw[row * 32 + permch(cp)],
                                               qw[row * 32 + permch(cp + 1)]));
    }
    for (int i = t; i < 1024; i += 256) {
      const int row = i >> 4, cp = (i & 15) * 2;
      wproj[i] = h2u(__builtin_amdgcn_cvt_pkrtz(pw[row * 32 + permch(cp)],
                                                pw[row * 32 + permch(cp + 1)]));
    }
    for (int i = t; i < 192; i += 256) bqkv[i] = qb[i];
    for (int i = t; i < 64; i += 256) bproj[i] = pbb[i];
    for (int i = t; i < 640; i += 256) {
      const int m = i & 7, r = i >> 3;
      const int n = r % 5, lh = r / 5;
      pb[i] = (m < 5) ? pp[lh * 25 + n * 5 + m] * LOG2E : 0.0f;
    }
  }
}

// A-fragment load: lane holds W[row][quad*8 .. quad*8+7] (8 contiguous fp16 = 16B)
__device__ __forceinline__ half8_t ldfrag(const uint4* __restrict__ w, int row, int quad) {
  H8 c; c.u4 = w[row * 4 + quad]; return c.h;
}
__device__ __forceinline__ half8_t mk8(const unsigned int (&d)[4]) {
  H8 c; c.u[0] = d[0]; c.u[1] = d[1]; c.u[2] = d[2]; c.u[3] = d[3]; return c.h;
}

// per-lane attention for one head. q/k packed fp16 pairs; v raw f32 MFMA acc.
// pbh points at [n][8]-padded, log2e-prescaled rows. No max-shift (bounded).
template <int NR>
__device__ __forceinline__ void attn_head(const unsigned int (&qd)[NR][2],
                                          const unsigned int (&kd)[NTOK][2],
                                          const f32x4 (&vv)[NTOK],
                                          const float* __restrict__ pbh,
                                          unsigned int (&od)[NR][2]) {
#pragma unroll
  for (int n = 0; n < NR; ++n) {
    const float4 pbv = *(const float4*)(pbh + n * 8);
    const float pb4 = pbh[n * 8 + 4];
    const float pbm[NTOK] = {pbv.x, pbv.y, pbv.z, pbv.w, pb4};
    const half2_t q0 = u2h(qd[n][0]), q1 = u2h(qd[n][1]);
    float e[NTOK];
#pragma unroll
    for (int m = 0; m < NTOK; ++m) {
      float d = __builtin_amdgcn_fdot2(q0, u2h(kd[m][0]), 0.0f, false);
      d = __builtin_amdgcn_fdot2(q1, u2h(kd[m][1]), d, false);
      // scale = HD^-0.5 * log2(e) = 0.5 * 1.44269504
      e[m] = __builtin_amdgcn_exp2f(fmaf(d, 0.72134752f, pbm[m]));
    }
    const float ssum = ((e[0] + e[1]) + (e[2] + e[3])) + e[4];
    const float r = __builtin_amdgcn_rcpf(ssum);
    f32x2 o01 = {0.0f, 0.0f}, o23 = {0.0f, 0.0f};
#pragma unroll
    for (int m = 0; m < NTOK; ++m) {
      const f32x2 em = {e[m], e[m]};
      const f32x2 vlo = {vv[m][0], vv[m][1]};
      const f32x2 vhi = {vv[m][2], vv[m][3]};
      o01 = __builtin_elementwise_fma(em, vlo, o01);
      o23 = __builtin_elementwise_fma(em, vhi, o23);
    }
    od[n][0] = pk(o01[0] * r, o01[1] * r);
    od[n][1] = pk(o23[0] * r, o23[1] * r);
  }
}

// ---------------- main kernel: 1 wave = 16 batch rows ----------------
__global__ __launch_bounds__(256, 4) void vit_kernel(
    const void* __restrict__ x, const void* __restrict__ token,
    const unsigned int* __restrict__ wqkv, const unsigned int* __restrict__ wproj,
    const float* __restrict__ bqkv, const float* __restrict__ bproj,
    const float* __restrict__ pb, const int* __restrict__ flag,
    void* __restrict__ out) {
  const int tid = threadIdx.x;
  const int wave = tid >> 6, lane = tid & 63;
  const int quad = lane >> 4, nl = lane & 15;
  const size_t b = (size_t)blockIdx.x * 64 + wave * 16 + nl;
  const int isbf = *flag;  // wave-uniform

  // y in pi layout: yd[t][j] = fp16 pair at pi-positions (8q+2j, 8q+2j+1),
  // i.e. true channels {4q..4q+3} (j<2) and {4q+16..4q+19} (j>=2).
  unsigned int yd[NTOK][4];
  if (isbf) {
    const unsigned short* tk = (const unsigned short*)token;
    const uint2 t0 = *(const uint2*)(tk + quad * 4);
    const uint2 t1 = *(const uint2*)(tk + quad * 4 + 16);
    yd[0][0] = h2u(bfpair2h2(t0.x)); yd[0][1] = h2u(bfpair2h2(t0.y));
    yd[0][2] = h2u(bfpair2h2(t1.x)); yd[0][3] = h2u(bfpair2h2(t1.y));
    const unsigned short* xb = (const unsigned short*)x + b * 128;
#pragma unroll
    for (int t = 1; t < NTOK; ++t) {
      const unsigned short* base = xb + (t - 1) * 32;
      const uint2 u0 = *(const uint2*)(base + quad * 4);
      const uint2 u1 = *(const uint2*)(base + quad * 4 + 16);
      yd[t][0] = h2u(bfpair2h2(u0.x)); yd[t][1] = h2u(bfpair2h2(u0.y));
      yd[t][2] = h2u(bfpair2h2(u1.x)); yd[t][3] = h2u(bfpair2h2(u1.y));
    }
  } else {
    const float* tk = (const float*)token;
    const float4 a0 = *(const float4*)(tk + quad * 4);
    const float4 a1 = *(const float4*)(tk + quad * 4 + 16);
    yd[0][0] = pk(a0.x, a0.y); yd[0][1] = pk(a0.z, a0.w);
    yd[0][2] = pk(a1.x, a1.y); yd[0][3] = pk(a1.z, a1.w);
    const float* xb = (const float*)x + b * 128;
#pragma unroll
    for (int t = 1; t < NTOK; ++t) {
      const float* base = xb + (t - 1) * 32;
      const float4 u0 = *(const float4*)(base + quad * 4);
      const float4 u1 = *(const float4*)(base + quad * 4 + 16);
      yd[t][0] = pk(u0.x, u0.y); yd[t][1] = pk(u0.z, u0.w);
      yd[t][2] = pk(u1.x, u1.y); yd[t][3] = pk(u1.z, u1.w);
    }
  }

  const uint4* wq4 = (const uint4*)wqkv;
  const uint4* wp4 = (const uint4*)wproj;

  // ===================== layer 0 =====================
  unsigned int od[2][NTOK][2];
#pragma unroll
  for (int s = 0; s < 2; ++s) {  // head-slot pass: tiles {s, 2+s, 4+s} = q,k,v of head quad+4s
    const half8_t waq = ldfrag(wq4, (s) * 16 + nl, quad);
    const half8_t wak = ldfrag(wq4, (2 + s) * 16 + nl, quad);
    const half8_t wav = ldfrag(wq4, (4 + s) * 16 + nl, quad);
    const f32x4 bq = *(const f32x4*)(bqkv + (s) * 16 + quad * 4);
    const f32x4 bk = *(const f32x4*)(bqkv + (2 + s) * 16 + quad * 4);
    const f32x4 bv = *(const f32x4*)(bqkv + (4 + s) * 16 + quad * 4);
    unsigned int qd[NTOK][2], kd[NTOK][2];
    f32x4 vv[NTOK];
#pragma unroll
    for (int t = 0; t < NTOK; ++t) {
      const half8_t yb = mk8(yd[t]);
      const f32x4 aq = __builtin_amdgcn_mfma_f32_16x16x32_f16(waq, yb, bq, 0, 0, 0);
      qd[t][0] = pk(aq[0], aq[1]); qd[t][1] = pk(aq[2], aq[3]);
      const f32x4 ak = __builtin_amdgcn_mfma_f32_16x16x32_f16(wak, yb, bk, 0, 0, 0);
      kd[t][0] = pk(ak[0], ak[1]); kd[t][1] = pk(ak[2], ak[3]);
      vv[t] = __builtin_amdgcn_mfma_f32_16x16x32_f16(wav, yb, bv, 0, 0, 0);
    }
    attn_head<NTOK>(qd, kd, vv, pb + (quad + 4 * s) * 40, od[s]);
  }

  {  // proj + residual; o natively pi layout -> direct B-operand; C natively pi
    half8_t wp[2]; f32x4 bp[2];
#pragma unroll
    for (int tile = 0; tile < 2; ++tile) {
      wp[tile] = ldfrag(wp4, tile * 16 + nl, quad);
      bp[tile] = *(const f32x4*)(bproj + tile * 16 + quad * 4);
    }
#pragma unroll
    for (int t = 0; t < NTOK; ++t) {
      unsigned int bfr[4] = {od[0][t][0], od[0][t][1], od[1][t][0], od[1][t][1]};
      const half8_t ob = mk8(bfr);
      f32x4 p0 = __builtin_amdgcn_mfma_f32_16x16x32_f16(wp[0], ob, bp[0], 0, 0, 0);
      f32x4 p1 = __builtin_amdgcn_mfma_f32_16x16x32_f16(wp[1], ob, bp[1], 0, 0, 0);
      yd[t][0] = h2u(u2h(yd[t][0]) + u2h(pk(p0[0], p0[1])));
      yd[t][1] = h2u(u2h(yd[t][1]) + u2h(pk(p0[2], p0[3])));
      yd[t][2] = h2u(u2h(yd[t][2]) + u2h(pk(p1[0], p1[1])));
      yd[t][3] = h2u(u2h(yd[t][3]) + u2h(pk(p1[2], p1[3])));
    }
  }

  // ===================== layer 1 (token-0 output only) =====================
  unsigned int o1[2][1][2];
#pragma unroll
  for (int s = 0; s < 2; ++s) {
    const half8_t waq = ldfrag(wq4, 96 + (s) * 16 + nl, quad);
    const half8_t wak = ldfrag(wq4, 96 + (2 + s) * 16 + nl, quad);
    const half8_t wav = ldfrag(wq4, 96 + (4 + s) * 16 + nl, quad);
    const f32x4 bq = *(const f32x4*)(bqkv + 96 + (s) * 16 + quad * 4);
    const f32x4 bk = *(const f32x4*)(bqkv + 96 + (2 + s) * 16 + quad * 4);
    const f32x4 bv = *(const f32x4*)(bqkv + 96 + (4 + s) * 16 + quad * 4);
    unsigned int qd[1][2], kd[NTOK][2];
    f32x4 vv[NTOK];
    {  // q: token 0 only
      const f32x4 aq = __builtin_amdgcn_mfma_f32_16x16x32_f16(waq, mk8(yd[0]), bq, 0, 0, 0);
      qd[0][0] = pk(aq[0], aq[1]); qd[0][1] = pk(aq[2], aq[3]);
    }
#pragma unroll
    for (int t = 0; t < NTOK; ++t) {
      const half8_t yb = mk8(yd[t]);
      const f32x4 ak = __builtin_amdgcn_mfma_f32_16x16x32_f16(wak, yb, bk, 0, 0, 0);
      kd[t][0] = pk(ak[0], ak[1]); kd[t][1] = pk(ak[2], ak[3]);
      vv[t] = __builtin_amdgcn_mfma_f32_16x16x32_f16(wav, yb, bv, 0, 0, 0);
    }
    attn_head<1>(qd, kd, vv, pb + (8 + quad + 4 * s) * 40, o1[s]);
  }

  {
    half8_t wp[2]; f32x4 bp[2];
#pragma unroll
    for (int tile = 0; tile < 2; ++tile) {
      wp[tile] = ldfrag(wp4, 32 + tile * 16 + nl, quad);
      bp[tile] = *(const f32x4*)(bproj + 32 + tile * 16 + quad * 4);
    }
    unsigned int bfr[4] = {o1[0][0][0], o1[0][0][1], o1[1][0][0], o1[1][0][1]};
    const half8_t ob = mk8(bfr);
    f32x4 p0 = __builtin_amdgcn_mfma_f32_16x16x32_f16(wp[0], ob, bp[0], 0, 0, 0);
    f32x4 p1 = __builtin_amdgcn_mfma_f32_16x16x32_f16(wp[1], ob, bp[1], 0, 0, 0);

    // f32-exact final residual; lane q holds channels {4q..4q+3, 4q+16..4q+19}
    const half2_t y0 = u2h(yd[0][0]), y1 = u2h(yd[0][1]);
    const half2_t y2 = u2h(yd[0][2]), y3 = u2h(yd[0][3]);
    float f[8] = {(float)y0.x + p0[0], (float)y0.y + p0[1],
                  (float)y1.x + p0[2], (float)y1.y + p0[3],
                  (float)y2.x + p1[0], (float)y2.y + p1[1],
                  (float)y3.x + p1[2], (float)y3.y + p1[3]};
    if (isbf) {
      unsigned short* ob16 = (unsigned short*)out + b * 32;
      *(uint2*)(ob16 + quad * 4) = make_uint2(f2bfpair(f[0], f[1]), f2bfpair(f[2], f[3]));
      *(uint2*)(ob16 + quad * 4 + 16) = make_uint2(f2bfpair(f[4], f[5]), f2bfpair(f[6], f[7]));
    } else {
      float* of = (float*)out + b * 32;
      *(float4*)(of + quad * 4) = make_float4(f[0], f[1], f[2], f[3]);
      *(float4*)(of + quad * 4 + 16) = make_float4(f[4], f[5], f[6], f[7]);
    }
  }
}

extern "C" void kernel_launch(void* const* d_in, const int* in_sizes, int n_in,
                              void* d_out, int out_size, void* d_ws, size_t ws_size,
                              hipStream_t stream) {
  const void* x      = d_in[0];
  const void* token  = d_in[1];
  const void* qkv_w  = d_in[2];
  const void* qkv_b  = d_in[3];
  const void* proj_w = d_in[4];
  const void* proj_b = d_in[5];
  const void* pos_b  = d_in[6];

  char* ws = (char*)d_ws;
  unsigned int* wqkv  = (unsigned int*)(ws + 0);
  unsigned int* wproj = (unsigned int*)(ws + 12288);
  float* bqkv  = (float*)(ws + 16384);
  float* bproj = (float*)(ws + 17152);
  float* pb    = (float*)(ws + 17408);   // 640 f32, [l][h][n][8] padded
  int*   flag  = (int*)(ws + 19968);

  prep_kernel<<<1, 256, 0, stream>>>(x, qkv_w, qkv_b, proj_w, proj_b, pos_b,
                                     wqkv, wproj, bqkv, bproj, pb, flag);

  const int nrows = in_sizes[0] / 128;  // 262144 batch rows
  const int grid = nrows / 64;          // 64 rows per 256-thread block (4 waves x 16)
  vit_kernel<<<grid, 256, 0, stream>>>(x, token, wqkv, wproj, bqkv, bproj, pb, flag, d_out);
}

// Round 3
// 232.878 us; speedup vs baseline: 1.0123x; 1.0123x over previous
//
#include <hip/hip_runtime.h>
#include <hip/hip_bf16.h>

// nnvit_82042465288319 on MI355X (gfx950). B=262144 rows; y[5][32]; 2 layers
// (H=8, HD=4); out = y[0] after layer 1. Inputs f32 (dtype probe keeps a bf16
// path for safety).
//
// Round 6 design (LDS-staged parameters; VMEM-queue decongestion):
//  - Theory: per-wave ~60 VMEM loads (weights/biases/pos_bias reloaded by
//    every wave) queue behind the x-streams of all 64 waves/CU -> each
//    dependent load inherits ~500+cy latency -> latency-serialized kernel.
//  - Fix: stage wqkv/wproj/bqkv/bproj/pb into LDS once per block (~24KB);
//    all reuse reads now on the LDS pipe (lgkmcnt, ~120cy, no VMEM queue).
//    Per-wave VMEM: 8 x-loads + ~5 staging + 2 stores.
//  - Weight rows padded to 80B in LDS: frag ds_read_b128 stride = 20 words
//    -> 2-way bank aliasing (free, m136). Bias/pb reads quad-broadcast.
//  - x raw-loaded BEFORE staging so HBM/L3 latency hides under stage+barrier.
//  - Keeps round-4/5 wins: pi-permuted channels (zero shuffles), f32 V,
//    padded pb rows, log2e-folded softmax without max-shift.

#define NTOK 5

typedef decltype(__builtin_amdgcn_cvt_pkrtz(0.0f, 0.0f)) half2_t;
using half8_t = __attribute__((ext_vector_type(8))) _Float16;
using f32x4 = __attribute__((ext_vector_type(4))) float;
using f32x2 = __attribute__((ext_vector_type(2))) float;

union H2 { half2_t h; unsigned int u; };
union H8 { half8_t h; uint4 u4; unsigned int u[4]; };

__device__ __forceinline__ half2_t u2h(unsigned int x) { H2 c; c.u = x; return c.h; }
__device__ __forceinline__ unsigned int h2u(half2_t h) { H2 c; c.h = h; return c.u; }
__device__ __forceinline__ unsigned int pk(float a, float b) {
  return h2u(__builtin_amdgcn_cvt_pkrtz(a, b));
}
__device__ __forceinline__ float bf2f(unsigned short u) {
  union { unsigned int u; float f; } c; c.u = ((unsigned int)u) << 16; return c.f;
}
__device__ __forceinline__ half2_t bfpair2h2(unsigned int u) {
  union { unsigned int u; float f; } lo, hi;
  lo.u = u << 16;
  hi.u = u & 0xffff0000u;
  return __builtin_amdgcn_cvt_pkrtz(lo.f, hi.f);  // exact: bf16 fits fp16 range here
}
// round-to-nearest-even f32 pair -> packed bf16 pair
__device__ __forceinline__ unsigned int f2bfpair(float a, float b) {
  unsigned int ua = __float_as_uint(a), ub = __float_as_uint(b);
  ua = (ua + 0x7fffu + ((ua >> 16) & 1u)) >> 16;
  ub = (ub + 0x7fffu + ((ub >> 16) & 1u)) & 0xffff0000u;
  return ua | ub;
}

// dtype probe: low 16 bits of each word form a normal-band bf16 exponent iff bf16
__device__ __forceinline__ int detect_bf16(const unsigned int* __restrict__ p) {
  int cnt = 0;
#pragma unroll
  for (int i = 0; i < 64; ++i) {
    unsigned int e = (p[i] >> 7) & 0xffu;
    cnt += (e >= 96u && e <= 150u) ? 1 : 0;
  }
  return (cnt >= 40) ? 1 : 0;
}

// channel permutation: pi(8q+j) = 4q + (j&3) + (j>=4 ? 16 : 0)
__device__ __forceinline__ int permch(int pos) {
  return 4 * (pos >> 3) + (pos & 3) + ((pos & 4) ? 16 : 0);
}

// ---------------- prep ----------------
// ws: wqkv u32[3072]@0 | wproj u32[1024]@12288 | bqkv f32[192]@16384
//     bproj f32[64]@17152 | pb f32[640]@17408 (layout [l][h][n][8], *log2e)
//     | flag int@19968
__global__ void prep_kernel(const void* __restrict__ xraw,
                            const void* __restrict__ qkv_w, const void* __restrict__ qkv_b,
                            const void* __restrict__ proj_w, const void* __restrict__ proj_b,
                            const void* __restrict__ pos_b,
                            unsigned int* __restrict__ wqkv, unsigned int* __restrict__ wproj,
                            float* __restrict__ bqkv, float* __restrict__ bproj,
                            float* __restrict__ pb, int* __restrict__ flag) {
  const int t = threadIdx.x;  // single block of 256
  const int isbf = detect_bf16((const unsigned int*)xraw);
  if (t == 0) *flag = isbf;
  const float LOG2E = 1.44269504f;
  if (isbf) {
    const unsigned short* qw = (const unsigned short*)qkv_w;
    const unsigned short* qb = (const unsigned short*)qkv_b;
    const unsigned short* pw = (const unsigned short*)proj_w;
    const unsigned short* pbb = (const unsigned short*)proj_b;
    const unsigned short* pp = (const unsigned short*)pos_b;
    for (int i = t; i < 3072; i += 256) {
      const int row = i >> 4, cp = (i & 15) * 2;
      wqkv[i] = h2u(__builtin_amdgcn_cvt_pkrtz(bf2f(qw[row * 32 + permch(cp)]),
                                               bf2f(qw[row * 32 + permch(cp + 1)])));
    }
    for (int i = t; i < 1024; i += 256) {
      const int row = i >> 4, cp = (i & 15) * 2;
      wproj[i] = h2u(__builtin_amdgcn_cvt_pkrtz(bf2f(pw[row * 32 + permch(cp)]),
                                                bf2f(pw[row * 32 + permch(cp + 1)])));
    }
    for (int i = t; i < 192; i += 256) bqkv[i] = bf2f(qb[i]);
    for (int i = t; i < 64; i += 256) bproj[i] = bf2f(pbb[i]);
    for (int i = t; i < 640; i += 256) {
      const int m = i & 7, r = i >> 3;       // r = lh*5 + n, lh in [0,16)
      const int n = r % 5, lh = r / 5;
      pb[i] = (m < 5) ? bf2f(pp[lh * 25 + n * 5 + m]) * LOG2E : 0.0f;
    }
  } else {
    const float* qw = (const float*)qkv_w;
    const float* qb = (const float*)qkv_b;
    const float* pw = (const float*)proj_w;
    const float* pbb = (const float*)proj_b;
    const float* pp = (const float*)pos_b;
    for (int i = t; i < 3072; i += 256) {
      const int row = i >> 4, cp = (i & 15) * 2;
      wqkv[i] = h2u(__builtin_amdgcn_cvt_pkrtz(qw[row * 32 + permch(cp)],
                                               qw[row * 32 + permch(cp + 1)]));
    }
    for (int i = t; i < 1024; i += 256) {
      const int row = i >> 4, cp = (i & 15) * 2;
      wproj[i] = h2u(__builtin_amdgcn_cvt_pkrtz(pw[row * 32 + permch(cp)],
                                                pw[row * 32 + permch(cp + 1)]));
    }
    for (int i = t; i < 192; i += 256) bqkv[i] = qb[i];
    for (int i = t; i < 64; i += 256) bproj[i] = pbb[i];
    for (int i = t; i < 640; i += 256) {
      const int m = i & 7, r = i >> 3;
      const int n = r % 5, lh = r / 5;
      pb[i] = (m < 5) ? pp[lh * 25 + n * 5 + m] * LOG2E : 0.0f;
    }
  }
}

__device__ __forceinline__ half8_t mk8(const unsigned int (&d)[4]) {
  H8 c; c.u[0] = d[0]; c.u[1] = d[1]; c.u[2] = d[2]; c.u[3] = d[3]; return c.h;
}

// LDS weight-frag read: rows padded to 80B (20 u32). lane holds
// W[row][quad*8 .. quad*8+7] (8 fp16 = 16B). Stride 20 words -> 2-way bank
// aliasing across 16 nl lanes (free per m136).
__device__ __forceinline__ half8_t ldsfrag(const unsigned int* lw, int row, int quad) {
  H8 c; c.u4 = *(const uint4*)(lw + row * 20 + quad * 4); return c.h;
}

// per-lane attention for one head. q/k packed fp16 pairs; v raw f32 MFMA acc.
// pbh points at [n][8]-padded, log2e-prescaled rows (in LDS). No max-shift.
template <int NR>
__device__ __forceinline__ void attn_head(const unsigned int (&qd)[NR][2],
                                          const unsigned int (&kd)[NTOK][2],
                                          const f32x4 (&vv)[NTOK],
                                          const float* pbh,
                                          unsigned int (&od)[NR][2]) {
#pragma unroll
  for (int n = 0; n < NR; ++n) {
    const f32x4 pbv = *(const f32x4*)(pbh + n * 8);
    const float pb4 = pbh[n * 8 + 4];
    const float pbm[NTOK] = {pbv[0], pbv[1], pbv[2], pbv[3], pb4};
    const half2_t q0 = u2h(qd[n][0]), q1 = u2h(qd[n][1]);
    float e[NTOK];
#pragma unroll
    for (int m = 0; m < NTOK; ++m) {
      float d = __builtin_amdgcn_fdot2(q0, u2h(kd[m][0]), 0.0f, false);
      d = __builtin_amdgcn_fdot2(q1, u2h(kd[m][1]), d, false);
      // scale = HD^-0.5 * log2(e) = 0.5 * 1.44269504
      e[m] = __builtin_amdgcn_exp2f(fmaf(d, 0.72134752f, pbm[m]));
    }
    const float ssum = ((e[0] + e[1]) + (e[2] + e[3])) + e[4];
    const float r = __builtin_amdgcn_rcpf(ssum);
    f32x2 o01 = {0.0f, 0.0f}, o23 = {0.0f, 0.0f};
#pragma unroll
    for (int m = 0; m < NTOK; ++m) {
      const f32x2 em = {e[m], e[m]};
      const f32x2 vlo = {vv[m][0], vv[m][1]};
      const f32x2 vhi = {vv[m][2], vv[m][3]};
      o01 = __builtin_elementwise_fma(em, vlo, o01);
      o23 = __builtin_elementwise_fma(em, vhi, o23);
    }
    od[n][0] = pk(o01[0] * r, o01[1] * r);
    od[n][1] = pk(o23[0] * r, o23[1] * r);
  }
}

// ---------------- main kernel: 1 wave = 16 batch rows ----------------
__global__ __launch_bounds__(256, 4) void vit_kernel(
    const void* __restrict__ x, const void* __restrict__ token,
    const unsigned int* __restrict__ wqkv, const unsigned int* __restrict__ wproj,
    const float* __restrict__ bqkv, const float* __restrict__ bproj,
    const float* __restrict__ pb, const int* __restrict__ flag,
    void* __restrict__ out) {
  // LDS parameter cache: 24,064 B/block -> 6 blocks/CU (24 waves) max.
  __shared__ unsigned int lds_w[256 * 20];  // rows 0..191 qkv, 192..255 proj; 80B rows
  __shared__ float lds_bq[192];
  __shared__ float lds_bp[64];
  __shared__ float lds_pb[640];

  const int tid = threadIdx.x;
  const int wave = tid >> 6, lane = tid & 63;
  const int quad = lane >> 4, nl = lane & 15;
  const size_t b = (size_t)blockIdx.x * 64 + wave * 16 + nl;
  const int isbf = *flag;  // wave-uniform

  // ---- issue raw x/token loads FIRST (longest latency; hides under staging+barrier)
  uint2 xb16[10];   // bf16 path raw
  float4 xf32[10];  // f32 path raw
  if (isbf) {
    const unsigned short* tk = (const unsigned short*)token;
    xb16[0] = *(const uint2*)(tk + quad * 4);
    xb16[1] = *(const uint2*)(tk + quad * 4 + 16);
    const unsigned short* xbp = (const unsigned short*)x + b * 128;
#pragma unroll
    for (int t = 1; t < NTOK; ++t) {
      const unsigned short* base = xbp + (t - 1) * 32;
      xb16[2 * t] = *(const uint2*)(base + quad * 4);
      xb16[2 * t + 1] = *(const uint2*)(base + quad * 4 + 16);
    }
  } else {
    const float* tk = (const float*)token;
    xf32[0] = *(const float4*)(tk + quad * 4);
    xf32[1] = *(const float4*)(tk + quad * 4 + 16);
    const float* xbp = (const float*)x + b * 128;
#pragma unroll
    for (int t = 1; t < NTOK; ++t) {
      const float* base = xbp + (t - 1) * 32;
      xf32[2 * t] = *(const float4*)(base + quad * 4);
      xf32[2 * t + 1] = *(const float4*)(base + quad * 4 + 16);
    }
  }

  // ---- stage parameters into LDS (global ws is small + L2-hot)
  {
    const uint4* sq = (const uint4*)wqkv;  // 768 uint4
#pragma unroll
    for (int k = 0; k < 3; ++k) {
      const int i = tid + k * 256;
      *(uint4*)(lds_w + (i >> 2) * 20 + (i & 3) * 4) = sq[i];
    }
    const uint4* sp = (const uint4*)wproj;  // 256 uint4
    *(uint4*)(lds_w + (192 + (tid >> 2)) * 20 + (tid & 3) * 4) = sp[tid];
    if (tid < 192) lds_bq[tid] = bqkv[tid];
    if (tid < 64) lds_bp[tid] = bproj[tid];
    {
      const uint4* spb = (const uint4*)pb;  // 160 uint4
      if (tid < 160) *(uint4*)((float*)lds_pb + tid * 4) = spb[tid];
    }
  }
  __syncthreads();

  // ---- convert x to y in pi layout: yd[t][j] = fp16 pair at pi-positions
  // (8q+2j, 8q+2j+1) = true chs {4q..4q+3} (j<2), {4q+16..4q+19} (j>=2).
  unsigned int yd[NTOK][4];
  if (isbf) {
#pragma unroll
    for (int t = 0; t < NTOK; ++t) {
      yd[t][0] = h2u(bfpair2h2(xb16[2 * t].x));
      yd[t][1] = h2u(bfpair2h2(xb16[2 * t].y));
      yd[t][2] = h2u(bfpair2h2(xb16[2 * t + 1].x));
      yd[t][3] = h2u(bfpair2h2(xb16[2 * t + 1].y));
    }
  } else {
#pragma unroll
    for (int t = 0; t < NTOK; ++t) {
      yd[t][0] = pk(xf32[2 * t].x, xf32[2 * t].y);
      yd[t][1] = pk(xf32[2 * t].z, xf32[2 * t].w);
      yd[t][2] = pk(xf32[2 * t + 1].x, xf32[2 * t + 1].y);
      yd[t][3] = pk(xf32[2 * t + 1].z, xf32[2 * t + 1].w);
    }
  }

  // ===================== layer 0 =====================
  unsigned int od[2][NTOK][2];
#pragma unroll
  for (int s = 0; s < 2; ++s) {  // head-slot pass: tiles {s, 2+s, 4+s} = q,k,v of head quad+4s
    const half8_t waq = ldsfrag(lds_w, (s) * 16 + nl, quad);
    const half8_t wak = ldsfrag(lds_w, (2 + s) * 16 + nl, quad);
    const half8_t wav = ldsfrag(lds_w, (4 + s) * 16 + nl, quad);
    const f32x4 bq = *(const f32x4*)(lds_bq + (s) * 16 + quad * 4);
    const f32x4 bk = *(const f32x4*)(lds_bq + (2 + s) * 16 + quad * 4);
    const f32x4 bv = *(const f32x4*)(lds_bq + (4 + s) * 16 + quad * 4);
    unsigned int qd[NTOK][2], kd[NTOK][2];
    f32x4 vv[NTOK];
#pragma unroll
    for (int t = 0; t < NTOK; ++t) {
      const half8_t yb = mk8(yd[t]);
      const f32x4 aq = __builtin_amdgcn_mfma_f32_16x16x32_f16(waq, yb, bq, 0, 0, 0);
      qd[t][0] = pk(aq[0], aq[1]); qd[t][1] = pk(aq[2], aq[3]);
      const f32x4 ak = __builtin_amdgcn_mfma_f32_16x16x32_f16(wak, yb, bk, 0, 0, 0);
      kd[t][0] = pk(ak[0], ak[1]); kd[t][1] = pk(ak[2], ak[3]);
      vv[t] = __builtin_amdgcn_mfma_f32_16x16x32_f16(wav, yb, bv, 0, 0, 0);
    }
    attn_head<NTOK>(qd, kd, vv, lds_pb + (quad + 4 * s) * 40, od[s]);
  }

  {  // proj + residual; o natively pi layout -> direct B-operand; C natively pi
    half8_t wp[2]; f32x4 bp[2];
#pragma unroll
    for (int tile = 0; tile < 2; ++tile) {
      wp[tile] = ldsfrag(lds_w, 192 + tile * 16 + nl, quad);
      bp[tile] = *(const f32x4*)(lds_bp + tile * 16 + quad * 4);
    }
#pragma unroll
    for (int t = 0; t < NTOK; ++t) {
      unsigned int bfr[4] = {od[0][t][0], od[0][t][1], od[1][t][0], od[1][t][1]};
      const half8_t ob = mk8(bfr);
      f32x4 p0 = __builtin_amdgcn_mfma_f32_16x16x32_f16(wp[0], ob, bp[0], 0, 0, 0);
      f32x4 p1 = __builtin_amdgcn_mfma_f32_16x16x32_f16(wp[1], ob, bp[1], 0, 0, 0);
      yd[t][0] = h2u(u2h(yd[t][0]) + u2h(pk(p0[0], p0[1])));
      yd[t][1] = h2u(u2h(yd[t][1]) + u2h(pk(p0[2], p0[3])));
      yd[t][2] = h2u(u2h(yd[t][2]) + u2h(pk(p1[0], p1[1])));
      yd[t][3] = h2u(u2h(yd[t][3]) + u2h(pk(p1[2], p1[3])));
    }
  }

  // ===================== layer 1 (token-0 output only) =====================
  unsigned int o1[2][1][2];
#pragma unroll
  for (int s = 0; s < 2; ++s) {
    const half8_t waq = ldsfrag(lds_w, 96 + (s) * 16 + nl, quad);
    const half8_t wak = ldsfrag(lds_w, 96 + (2 + s) * 16 + nl, quad);
    const half8_t wav = ldsfrag(lds_w, 96 + (4 + s) * 16 + nl, quad);
    const f32x4 bq = *(const f32x4*)(lds_bq + 96 + (s) * 16 + quad * 4);
    const f32x4 bk = *(const f32x4*)(lds_bq + 96 + (2 + s) * 16 + quad * 4);
    const f32x4 bv = *(const f32x4*)(lds_bq + 96 + (4 + s) * 16 + quad * 4);
    unsigned int qd[1][2], kd[NTOK][2];
    f32x4 vv[NTOK];
    {  // q: token 0 only
      const f32x4 aq = __builtin_amdgcn_mfma_f32_16x16x32_f16(waq, mk8(yd[0]), bq, 0, 0, 0);
      qd[0][0] = pk(aq[0], aq[1]); qd[0][1] = pk(aq[2], aq[3]);
    }
#pragma unroll
    for (int t = 0; t < NTOK; ++t) {
      const half8_t yb = mk8(yd[t]);
      const f32x4 ak = __builtin_amdgcn_mfma_f32_16x16x32_f16(wak, yb, bk, 0, 0, 0);
      kd[t][0] = pk(ak[0], ak[1]); kd[t][1] = pk(ak[2], ak[3]);
      vv[t] = __builtin_amdgcn_mfma_f32_16x16x32_f16(wav, yb, bv, 0, 0, 0);
    }
    attn_head<1>(qd, kd, vv, lds_pb + (8 + quad + 4 * s) * 40, o1[s]);
  }

  {
    half8_t wp[2]; f32x4 bp[2];
#pragma unroll
    for (int tile = 0; tile < 2; ++tile) {
      wp[tile] = ldsfrag(lds_w, 192 + 32 + tile * 16 + nl, quad);
      bp[tile] = *(const f32x4*)(lds_bp + 32 + tile * 16 + quad * 4);
    }
    unsigned int bfr[4] = {o1[0][0][0], o1[0][0][1], o1[1][0][0], o1[1][0][1]};
    const half8_t ob = mk8(bfr);
    f32x4 p0 = __builtin_amdgcn_mfma_f32_16x16x32_f16(wp[0], ob, bp[0], 0, 0, 0);
    f32x4 p1 = __builtin_amdgcn_mfma_f32_16x16x32_f16(wp[1], ob, bp[1], 0, 0, 0);

    // f32-exact final residual; lane q holds channels {4q..4q+3, 4q+16..4q+19}
    const half2_t y0 = u2h(yd[0][0]), y1 = u2h(yd[0][1]);
    const half2_t y2 = u2h(yd[0][2]), y3 = u2h(yd[0][3]);
    float f[8] = {(float)y0.x + p0[0], (float)y0.y + p0[1],
                  (float)y1.x + p0[2], (float)y1.y + p0[3],
                  (float)y2.x + p1[0], (float)y2.y + p1[1],
                  (float)y3.x + p1[2], (float)y3.y + p1[3]};
    if (isbf) {
      unsigned short* ob16 = (unsigned short*)out + b * 32;
      *(uint2*)(ob16 + quad * 4) = make_uint2(f2bfpair(f[0], f[1]), f2bfpair(f[2], f[3]));
      *(uint2*)(ob16 + quad * 4 + 16) = make_uint2(f2bfpair(f[4], f[5]), f2bfpair(f[6], f[7]));
    } else {
      float* of = (float*)out + b * 32;
      *(float4*)(of + quad * 4) = make_float4(f[0], f[1], f[2], f[3]);
      *(float4*)(of + quad * 4 + 16) = make_float4(f[4], f[5], f[6], f[7]);
    }
  }
}

extern "C" void kernel_launch(void* const* d_in, const int* in_sizes, int n_in,
                              void* d_out, int out_size, void* d_ws, size_t ws_size,
                              hipStream_t stream) {
  const void* x      = d_in[0];
  const void* token  = d_in[1];
  const void* qkv_w  = d_in[2];
  const void* qkv_b  = d_in[3];
  const void* proj_w = d_in[4];
  const void* proj_b = d_in[5];
  const void* pos_b  = d_in[6];

  char* ws = (char*)d_ws;
  unsigned int* wqkv  = (unsigned int*)(ws + 0);
  unsigned int* wproj = (unsigned int*)(ws + 12288);
  float* bqkv  = (float*)(ws + 16384);
  float* bproj = (float*)(ws + 17152);
  float* pb    = (float*)(ws + 17408);   // 640 f32, [l][h][n][8] padded
  int*   flag  = (int*)(ws + 19968);

  prep_kernel<<<1, 256, 0, stream>>>(x, qkv_w, qkv_b, proj_w, proj_b, pos_b,
                                     wqkv, wproj, bqkv, bproj, pb, flag);

  const int nrows = in_sizes[0] / 128;  // 262144 batch rows
  const int grid = nrows / 64;          // 64 rows per 256-thread block (4 waves x 16)
  vit_kernel<<<grid, 256, 0, stream>>>(x, token, wqkv, wproj, bqkv, bproj, pb, flag, d_out);
}